// Round 6
// baseline (75.361 us; speedup 1.0000x reference)
//
#include <hip/hip_runtime.h>

#define NB 256
#define NP 512
#define NE 256
#define NH 128

typedef __attribute__((ext_vector_type(8))) short bf16x8;
typedef __attribute__((ext_vector_type(4))) float f32x4;

__device__ __forceinline__ short f2bf(float f) {
  union { float f; unsigned u; } v; v.f = f;
  unsigned r = v.u + 0x7fffu + ((v.u >> 16) & 1u);   // RNE
  return (short)(r >> 16);
}
// tanh(x) = 1 - 2/(exp2(2*log2e*x)+1)
__device__ __forceinline__ float fast_tanh(float x) {
  float u = __builtin_amdgcn_exp2f(x * 2.8853900817779268f);
  return 1.0f - 2.0f * __builtin_amdgcn_rcpf(u + 1.0f);
}

// ---- prologue: w1 fp32 -> bf16 (64 KB, stays L2-hot for the main kernel) ----
__global__ void pathattn_w1cvt(const float* __restrict__ w1,
                               short* __restrict__ w1b) {
  const int i = blockIdx.x * 256 + threadIdx.x;   // grid 128 x 256 = 32768
  w1b[i] = f2bf(w1[i]);
}

// ---- main: one wave owns 32 p-rows end-to-end. No LDS / no barriers in the
// main loop; scores via MFMA with A-frags streamed from L2 (w1b) and B-frags
// loaded directly from global x (L3-resident on timed replays). ----
__global__ __launch_bounds__(256, 2) void pathattn_main(
    const float* __restrict__ x, const short* __restrict__ w1b,
    const float* __restrict__ w2, float* __restrict__ wsPool,
    float* __restrict__ wsZ) {
  __shared__ float pool[4][NE];
  __shared__ float zsh[4];

  const int tid  = threadIdx.x;
  const int lane = tid & 63;
  const int wid  = tid >> 6;            // 0..3
  const int n15  = lane & 15;
  const int l4   = lane >> 4;           // 0..3
  const int b    = blockIdx.x >> 2;
  const int quarter = blockIdx.x & 3;
  const int p0   = quarter * 128 + wid * 32;      // this wave's 32 p-rows
  const float* xb = x + (size_t)b * NP * NE;

  // ---- score MFMAs: D[h][p] = sum_k w1[h][k] * x[p][k], 128h x 32p ----
  f32x4 acc[2][8];
  #pragma unroll
  for (int pg = 0; pg < 2; ++pg)
    #pragma unroll
    for (int ht = 0; ht < 8; ++ht) acc[pg][ht] = (f32x4){0.f,0.f,0.f,0.f};

  #pragma unroll 1                      // do NOT hoist all loads (spill guard)
  for (int kt = 0; kt < 8; ++kt) {
    const int kbase = kt * 32 + l4 * 8;
    // B-frags: lane holds p = p0 + pg*16 + n15, k = kbase..kbase+7
    bf16x8 bfrag0, bfrag1;
    {
      const float* s = xb + (size_t)(p0 + n15) * NE + kbase;
      f32x4 a = *(const f32x4*)s, c = *(const f32x4*)(s + 4);
      bf16x8 v;
      v[0]=f2bf(a[0]); v[1]=f2bf(a[1]); v[2]=f2bf(a[2]); v[3]=f2bf(a[3]);
      v[4]=f2bf(c[0]); v[5]=f2bf(c[1]); v[6]=f2bf(c[2]); v[7]=f2bf(c[3]);
      bfrag0 = v;
    }
    {
      const float* s = xb + (size_t)(p0 + 16 + n15) * NE + kbase;
      f32x4 a = *(const f32x4*)s, c = *(const f32x4*)(s + 4);
      bf16x8 v;
      v[0]=f2bf(a[0]); v[1]=f2bf(a[1]); v[2]=f2bf(a[2]); v[3]=f2bf(a[3]);
      v[4]=f2bf(c[0]); v[5]=f2bf(c[1]); v[6]=f2bf(c[2]); v[7]=f2bf(c[3]);
      bfrag1 = v;
    }
    // A-frags from bf16 w1b (L2-hot): lane holds h-row = ht*16+n15, same k
    #pragma unroll
    for (int ht = 0; ht < 8; ++ht) {
      bf16x8 av = *(const bf16x8*)(w1b + (ht * 16 + n15) * NE + kbase);
      acc[0][ht] = __builtin_amdgcn_mfma_f32_16x16x32_bf16(av, bfrag0, acc[0][ht], 0, 0, 0);
      acc[1][ht] = __builtin_amdgcn_mfma_f32_16x16x32_bf16(av, bfrag1, acc[1][ht], 0, 0, 0);
    }
  }

  // ---- tanh * w2, reduce over h (3 local + 2 shuffles), exp ----
  // D layout: col(p) = lane&15, row(h) = ht*16 + l4*4 + r
  float s0 = 0.f, s1 = 0.f;
  #pragma unroll
  for (int ht = 0; ht < 8; ++ht) {
    f32x4 wv = *(const f32x4*)(w2 + ht * 16 + l4 * 4);
    #pragma unroll
    for (int r = 0; r < 4; ++r) {
      s0 += fast_tanh(acc[0][ht][r]) * wv[r];
      s1 += fast_tanh(acc[1][ht][r]) * wv[r];
    }
  }
  s0 += __shfl_xor(s0, 16, 64); s0 += __shfl_xor(s0, 32, 64);
  s1 += __shfl_xor(s1, 16, 64); s1 += __shfl_xor(s1, 32, 64);
  // no max-subtraction needed: |s| <= ||w2||_1 <= 12.8
  const float e0 = __builtin_amdgcn_exp2f(s0 * 1.4426950408889634f);
  const float e1 = __builtin_amdgcn_exp2f(s1 * 1.4426950408889634f);
  float zacc = e0 + e1;                 // 4x replicated across l4 groups

  // ---- pooling in fp32 straight from x (rows L1/L2-hot): 32 rows ----
  f32x4 pacc = {0.f, 0.f, 0.f, 0.f};
  #pragma unroll 1
  for (int pp = 0; pp < 16; ++pp) {
    const float ep = __shfl(e0, pp, 64);
    f32x4 v = *(const f32x4*)(xb + (size_t)(p0 + pp) * NE + lane * 4);
    pacc[0] += ep * v[0]; pacc[1] += ep * v[1];
    pacc[2] += ep * v[2]; pacc[3] += ep * v[3];
  }
  #pragma unroll 1
  for (int pp = 0; pp < 16; ++pp) {
    const float ep = __shfl(e1, pp, 64);
    f32x4 v = *(const f32x4*)(xb + (size_t)(p0 + 16 + pp) * NE + lane * 4);
    pacc[0] += ep * v[0]; pacc[1] += ep * v[1];
    pacc[2] += ep * v[2]; pacc[3] += ep * v[3];
  }

  // ---- epilogue: combine 4 waves, write block partial ----
  *(f32x4*)(&pool[wid][lane * 4]) = pacc;
  #pragma unroll
  for (int m = 1; m <= 32; m <<= 1) zacc += __shfl_xor(zacc, m, 64);
  if (lane == 0) zsh[wid] = zacc * 0.25f;       // undo 4x l4 replication
  __syncthreads();
  float v = pool[0][tid] + pool[1][tid] + pool[2][tid] + pool[3][tid];
  wsPool[(size_t)blockIdx.x * NE + tid] = v;
  if (tid == 0)
    wsZ[blockIdx.x] = zsh[0] + zsh[1] + zsh[2] + zsh[3];
}

// ---- combine the four P-quarters and normalize ----
__global__ void pathattn_combine(const float* __restrict__ wsPool,
                                 const float* __restrict__ wsZ,
                                 float* __restrict__ out) {
  const int b = blockIdx.x, e = threadIdx.x;
  float v = 0.f, z = 0.f;
  #pragma unroll
  for (int q = 0; q < 4; ++q) {
    v += wsPool[(size_t)(4 * b + q) * NE + e];
    z += wsZ[4 * b + q];
  }
  out[(size_t)b * NE + e] = v / z;
}

extern "C" void kernel_launch(void* const* d_in, const int* in_sizes, int n_in,
                              void* d_out, int out_size, void* d_ws, size_t ws_size,
                              hipStream_t stream) {
  (void)in_sizes; (void)n_in; (void)out_size; (void)ws_size;
  const float* x  = (const float*)d_in[0];
  const float* w1 = (const float*)d_in[1];
  const float* w2 = (const float*)d_in[2];
  float* out = (float*)d_out;
  short* w1b    = (short*)d_ws;                    // [128*256] bf16 (64 KB)
  float* wsPool = (float*)((char*)d_ws + 65536);   // [1024][256] f32
  float* wsZ    = wsPool + 1024 * NE;              // [1024] f32
  pathattn_w1cvt<<<NH * NE / 256, 256, 0, stream>>>(w1, w1b);
  pathattn_main<<<4 * NB, 256, 0, stream>>>(x, w1b, w2, wsPool, wsZ);
  pathattn_combine<<<NB, NE, 0, stream>>>(wsPool, wsZ, out);
}

// Round 7
// 62.521 us; speedup vs baseline: 1.2054x; 1.2054x over previous
//
#include <hip/hip_runtime.h>

#define NB 256
#define NP 512
#define NE 256
#define NH 128
#define PW 32              // p-rows per wave (wave-autonomous tile)

typedef __attribute__((ext_vector_type(8))) short bf16x8;
typedef __attribute__((ext_vector_type(4))) short s16x4;
typedef __attribute__((ext_vector_type(4))) float f32x4;

__device__ __forceinline__ short f2bf(float f) {
  union { float f; unsigned u; } v; v.f = f;
  unsigned r = v.u + 0x7fffu + ((v.u >> 16) & 1u);   // RNE
  return (short)(r >> 16);
}
__device__ __forceinline__ float bf2f(short s) {
  union { unsigned u; float f; } v;
  v.u = ((unsigned)(unsigned short)s) << 16;
  return v.f;
}
// tanh(x) = 1 - 2/(exp2(2*log2e*x)+1)
__device__ __forceinline__ float fast_tanh(float x) {
  float u = __builtin_amdgcn_exp2f(x * 2.8853900817779268f);
  return 1.0f - 2.0f * __builtin_amdgcn_rcpf(u + 1.0f);
}

// ---- prologue: w1 fp32 -> bf16 (64 KB, L2-hot for the main kernel) ----
__global__ void pathattn_w1cvt(const float* __restrict__ w1,
                               short* __restrict__ w1b) {
  const int i = blockIdx.x * 256 + threadIdx.x;
  w1b[i] = f2bf(w1[i]);
}

// ---- main: one wave owns 32 p-rows end-to-end. Wave-private LDS tile,
// ZERO barriers in the main work (single __syncthreads only at epilogue). ----
__global__ __launch_bounds__(256, 2) void pathattn_main(
    const float* __restrict__ x, const short* __restrict__ w1b,
    const float* __restrict__ w2, float* __restrict__ wsPool,
    float* __restrict__ wsZ) {
  // 4 wave-private 16 KB tiles (XOR-swizzled) + epilogue scratch
  __shared__ short xtile[4][PW * NE];
  __shared__ float pool[4][NE];
  __shared__ float zsh[4];

  const int tid  = threadIdx.x;
  const int lane = tid & 63;
  const int wid  = tid >> 6;            // 0..3
  const int n15  = lane & 15;
  const int l4   = lane >> 4;           // 0..3
  const int b    = blockIdx.x >> 2;
  const int quarter = blockIdx.x & 3;
  const int p0   = quarter * 128 + wid * PW;      // wave's 32 p-rows
  const float* xb = x + (size_t)b * NP * NE;
  short* myt = &xtile[wid][0];

  // ---- stage wave's 32x256 fp32 rows -> bf16 LDS, coalesced (1 row/instr),
  // 8 loads in flight per batch. Swizzle: short col ^= (row&7)<<3. ----
  {
    const float* src = xb + (size_t)p0 * NE;
    #pragma unroll
    for (int bb = 0; bb < 4; ++bb) {
      f32x4 r[8];
      #pragma unroll
      for (int i = 0; i < 8; ++i)
        r[i] = *(const f32x4*)(src + (size_t)(bb * 8 + i) * NE + lane * 4);
      #pragma unroll
      for (int i = 0; i < 8; ++i) {
        const int row = bb * 8 + i;
        s16x4 v;
        v[0] = f2bf(r[i][0]); v[1] = f2bf(r[i][1]);
        v[2] = f2bf(r[i][2]); v[3] = f2bf(r[i][3]);
        *(s16x4*)(myt + row * NE + ((lane * 4) ^ ((row & 7) << 3))) = v;
      }
    }
  }

  // ---- score MFMAs: D[h][p] = sum_k w1[h][k]*x[p][k]; 128h x 32p/wave ----
  f32x4 acc[2][8];
  #pragma unroll
  for (int pg = 0; pg < 2; ++pg)
    #pragma unroll
    for (int ht = 0; ht < 8; ++ht) acc[pg][ht] = (f32x4){0.f,0.f,0.f,0.f};

  #pragma unroll
  for (int kt = 0; kt < 8; ++kt) {
    const int kbase = kt * 32 + l4 * 8;
    // B-frags from private LDS (swizzled)
    const int r0 = n15, r1 = 16 + n15;
    bf16x8 bv0 = *(const bf16x8*)(myt + r0 * NE + (kbase ^ ((r0 & 7) << 3)));
    bf16x8 bv1 = *(const bf16x8*)(myt + r1 * NE + (kbase ^ ((r1 & 7) << 3)));
    // A-frags from L2-hot bf16 w1 (16 rows x 64B segments per instr)
    bf16x8 av[8];
    #pragma unroll
    for (int ht = 0; ht < 8; ++ht)
      av[ht] = *(const bf16x8*)(w1b + (ht * 16 + n15) * NE + kbase);
    #pragma unroll
    for (int ht = 0; ht < 8; ++ht) {
      acc[0][ht] = __builtin_amdgcn_mfma_f32_16x16x32_bf16(av[ht], bv0, acc[0][ht], 0, 0, 0);
      acc[1][ht] = __builtin_amdgcn_mfma_f32_16x16x32_bf16(av[ht], bv1, acc[1][ht], 0, 0, 0);
    }
  }

  // ---- tanh * w2, reduce over h (local + 2 shuffles), exp ----
  // D layout: col(p)=lane&15, row(h)=ht*16 + l4*4 + r
  float s0 = 0.f, s1 = 0.f;
  #pragma unroll
  for (int ht = 0; ht < 8; ++ht) {
    f32x4 wv = *(const f32x4*)(w2 + ht * 16 + l4 * 4);
    #pragma unroll
    for (int r = 0; r < 4; ++r) {
      s0 += fast_tanh(acc[0][ht][r]) * wv[r];
      s1 += fast_tanh(acc[1][ht][r]) * wv[r];
    }
  }
  s0 += __shfl_xor(s0, 16, 64); s0 += __shfl_xor(s0, 32, 64);
  s1 += __shfl_xor(s1, 16, 64); s1 += __shfl_xor(s1, 32, 64);
  // no max-subtraction needed: |s| <= ||w2||_1 <= 12.8
  const float e0 = __builtin_amdgcn_exp2f(s0 * 1.4426950408889634f);
  const float e1 = __builtin_amdgcn_exp2f(s1 * 1.4426950408889634f);
  float zacc = e0 + e1;                 // 4x replicated across l4 groups

  // ---- pooling from private LDS: row-broadcast reads, conflict-free ----
  f32x4 pacc = {0.f, 0.f, 0.f, 0.f};
  #pragma unroll
  for (int pp = 0; pp < 16; ++pp) {
    const float ep = __shfl(e0, pp, 64);
    s16x4 v = *(const s16x4*)(myt + pp * NE + ((lane * 4) ^ ((pp & 7) << 3)));
    pacc[0] += ep * bf2f(v[0]); pacc[1] += ep * bf2f(v[1]);
    pacc[2] += ep * bf2f(v[2]); pacc[3] += ep * bf2f(v[3]);
  }
  #pragma unroll
  for (int pp = 0; pp < 16; ++pp) {
    const float ep = __shfl(e1, pp, 64);
    const int row = 16 + pp;
    s16x4 v = *(const s16x4*)(myt + row * NE + ((lane * 4) ^ ((pp & 7) << 3)));
    pacc[0] += ep * bf2f(v[0]); pacc[1] += ep * bf2f(v[1]);
    pacc[2] += ep * bf2f(v[2]); pacc[3] += ep * bf2f(v[3]);
  }

  // ---- epilogue: single barrier, combine 4 waves, write block partial ----
  *(f32x4*)(&pool[wid][lane * 4]) = pacc;
  #pragma unroll
  for (int m = 1; m <= 32; m <<= 1) zacc += __shfl_xor(zacc, m, 64);
  if (lane == 0) zsh[wid] = zacc * 0.25f;       // undo 4x l4 replication
  __syncthreads();
  float v = pool[0][tid] + pool[1][tid] + pool[2][tid] + pool[3][tid];
  wsPool[(size_t)blockIdx.x * NE + tid] = v;
  if (tid == 0)
    wsZ[blockIdx.x] = zsh[0] + zsh[1] + zsh[2] + zsh[3];
}

// ---- combine the four P-quarters and normalize ----
__global__ void pathattn_combine(const float* __restrict__ wsPool,
                                 const float* __restrict__ wsZ,
                                 float* __restrict__ out) {
  const int b = blockIdx.x, e = threadIdx.x;
  float v = 0.f, z = 0.f;
  #pragma unroll
  for (int q = 0; q < 4; ++q) {
    v += wsPool[(size_t)(4 * b + q) * NE + e];
    z += wsZ[4 * b + q];
  }
  out[(size_t)b * NE + e] = v / z;
}

extern "C" void kernel_launch(void* const* d_in, const int* in_sizes, int n_in,
                              void* d_out, int out_size, void* d_ws, size_t ws_size,
                              hipStream_t stream) {
  (void)in_sizes; (void)n_in; (void)out_size; (void)ws_size;
  const float* x  = (const float*)d_in[0];
  const float* w1 = (const float*)d_in[1];
  const float* w2 = (const float*)d_in[2];
  float* out = (float*)d_out;
  short* w1b    = (short*)d_ws;                    // [128*256] bf16 (64 KB)
  float* wsPool = (float*)((char*)d_ws + 65536);   // [1024][256] f32
  float* wsZ    = wsPool + 1024 * NE;              // [1024] f32
  pathattn_w1cvt<<<NH * NE / 256, 256, 0, stream>>>(w1, w1b);
  pathattn_main<<<4 * NB, 256, 0, stream>>>(x, w1b, w2, wsPool, wsZ);
  pathattn_combine<<<NB, NE, 0, stream>>>(wsPool, wsZ, out);
}